// Round 1
// baseline (9347.830 us; speedup 1.0000x reference)
//
#include <hip/hip_runtime.h>
#include <math.h>

#define NPTS 3072
#define BLK  512
#define PPT  (NPTS / BLK)   // 6 points per thread
#define NCLS 10
#define NWAVE (BLK / 64)

#pragma clang fp contract(off)

__device__ __forceinline__ unsigned long long u64min(unsigned long long a, unsigned long long b) {
    return a < b ? a : b;
}

__global__ __launch_bounds__(BLK)
void frustum_cluster(const float* __restrict__ pts,
                     const int* __restrict__ lblg,
                     const float* __restrict__ anch,
                     int* __restrict__ out,
                     int* __restrict__ ws)
{
    // ---- LDS: one 61440B buffer, phase-reused ----
    __shared__ float sm[15360];
    float* px = sm;                                       // [0,3072) scan: points x
    float* py = sm + 3072;
    float* pz = sm + 6144;
    int*   lb = (int*)(sm + 9216);                        // labels
    unsigned short* dl  = (unsigned short*)(sm + 12288);  // dist_labels (6KB)
    unsigned short* vor = (unsigned short*)(sm + 13824);  // visit order (6KB)
    __shared__ float pmin[NWAVE], pmax[NWAVE];
    __shared__ unsigned long long parg[NWAVE];
    __shared__ float s_pcx, s_pcy, s_pcz;
    __shared__ int   s_cls, s_lab;
    __shared__ float amdxy[NCLS], amdz[NCLS], r2a[NCLS];

    const int tid  = threadIdx.x;
    const int lane = tid & 63;
    const int wid  = tid >> 6;

    // ---- global workspace layout (9 * 12KB = 108KB) ----
    int*   startw = ws;
    int*   countg = ws + NPTS;
    float* cxg    = (float*)(ws + 2*NPTS);
    float* cyg    = (float*)(ws + 3*NPTS);
    float* czg    = (float*)(ws + 4*NPTS);
    int*   ccg    = ws + 5*NPTS;
    int*   orderg = ws + 6*NPTS;
    int*   remapg = ws + 7*NPTS;
    int*   dlg    = ws + 8*NPTS;

    // ---- stage inputs into LDS ----
    for (int i = tid; i < NPTS*3; i += BLK) {
        float v = pts[i];
        int r = i / 3, c = i - 3*r;
        if (c == 0) px[r] = v; else if (c == 1) py[r] = v; else pz[r] = v;
    }
    for (int j = tid; j < NPTS; j += BLK) lb[j] = lblg[j];
    if (tid < NCLS) {
        float l = anch[tid*3], w = anch[tid*3+1], h = anch[tid*3+2];
        amdxy[tid] = fmaxf(l, w);
        amdz[tid]  = h;
        r2a[tid]   = sqrtf((l*l + w*w) + h*h) / 2.0f;   // norm(anchor)/2, left-to-right sum
    }
    if (tid == 0) { dl[0] = 0; vor[0] = 0; }
    __syncthreads();
    if (tid == 0) { s_pcx = px[0]; s_pcy = py[0]; s_pcz = pz[0]; s_cls = lb[0]; }

    // per-thread owned points in registers
    float pox[PPT], poy[PPT], poz[PPT];
    int   lol[PPT];
    int   vis = 0;
    const int base = tid * PPT;
    #pragma unroll
    for (int k = 0; k < PPT; ++k) {
        pox[k] = px[base+k]; poy[k] = py[base+k]; poz[k] = pz[base+k];
        lol[k] = lb[base+k];
    }
    if (base == 0) vis |= 1;                 // point 0 starts visited (dl[0]=0)
    // thread-0 incremental cluster state (centre sum of current cluster)
    float sx = 0.f, sy = 0.f, sz = 0.f, scnt = 0.f;
    int lab = 0;
    if (tid == 0) { sx = px[0]; sy = py[0]; sz = pz[0]; scnt = 1.0f; }
    __syncthreads();

    // ---- main greedy scan: 3071 sequential steps, 3 barriers each ----
    for (int t = 0; t < NPTS-1; ++t) {
        const float pcx = s_pcx, pcy = s_pcy, pcz = s_pcz;
        const int   cls = s_cls;
        float dr[PPT];
        float dmn = INFINITY, dmx = -INFINITY;
        #pragma unroll
        for (int k = 0; k < PPT; ++k) {
            float dx = pcx - pox[k], dy = pcy - poy[k], dz = pcz - poz[k];
            float d = sqrtf((dx*dx + dy*dy) + dz*dz);   // == ref dists (sign-flipped diff squares identical)
            dr[k] = d;
            if (!((vis >> k) & 1)) { dmn = fminf(dmn, d); dmx = fmaxf(dmx, d); }
        }
        #pragma unroll
        for (int off = 32; off > 0; off >>= 1) {
            dmn = fminf(dmn, __shfl_xor(dmn, off, 64));
            dmx = fmaxf(dmx, __shfl_xor(dmx, off, 64));
        }
        if (lane == 0) { pmin[wid] = dmn; pmax[wid] = dmx; }
        __syncthreads();
        float dmnS = pmin[0], dmxS = pmax[0];
        #pragma unroll
        for (int w = 1; w < NWAVE; ++w) { dmnS = fminf(dmnS, pmin[w]); dmxS = fmaxf(dmxS, pmax[w]); }
        const float rng = (dmxS - dmnS) + 1e-8f;        // ref op order
        unsigned long long best = ~0ull;
        #pragma unroll
        for (int k = 0; k < PPT; ++k) {
            if (!((vis >> k) & 1)) {
                float cost = ((dr[k] - dmnS) / rng) + ((lol[k] != cls) ? 1.0f : 0.0f);
                // nonneg float bits are order-monotone; low 32 bits = index -> first-min tiebreak
                unsigned long long key = ((unsigned long long)__float_as_uint(cost) << 32)
                                       | (unsigned)(base + k);
                best = u64min(best, key);
            }
        }
        #pragma unroll
        for (int off = 32; off > 0; off >>= 1)
            best = u64min(best, __shfl_xor(best, off, 64));
        if (lane == 0) parg[wid] = best;
        __syncthreads();
        unsigned long long b = parg[0];
        #pragma unroll
        for (int w = 1; w < NWAVE; ++w) b = u64min(b, parg[w]);
        const int ci = (int)(unsigned)(b & 0xffffffffu);
        if (ci >= base && ci < base + PPT) vis |= 1 << (ci - base);
        if (tid == 0) {
            float pix = px[ci], piy = py[ci], piz = pz[ci];
            int   lci = lb[ci];
            float dx = pcx - pix, dy = pcy - piy, dz = pcz - piz;
            // NOTE: angle clause omitted — max over cm includes angle(cur,cur)=acos(0)=pi/2_f,
            // so (max < pi/2) is structurally always False in the reference.
            bool nc = (fabsf(dx) > amdxy[cls]) || (fabsf(dy) > amdxy[cls]) || (fabsf(dz) > amdz[cls]);
            nc = nc || (lci != cls);
            float dn = sqrtf((dx*dx + dy*dy) + dz*dz);
            float r2 = r2a[cls];
            nc = nc || (dn > r2);
            float ex = (sx / scnt) - pix;
            float ey = (sy / scnt) - piy;
            float ez = (sz / scnt) - piz;
            float en = sqrtf((ex*ex + ey*ey) + ez*ez);
            nc = nc || (en > r2);
            if (nc) { lab++; sx = pix; sy = piy; sz = piz; scnt = 1.0f; }
            else    { sx = sx + pix; sy = sy + piy; sz = sz + piz; scnt = scnt + 1.0f; }
            dl[ci]   = (unsigned short)lab;
            vor[t+1] = (unsigned short)ci;
            s_pcx = pix; s_pcy = piy; s_pcz = piz; s_cls = lci;
            if (t == NPTS-2) s_lab = lab;
        }
        __syncthreads();
    }

    const int nclus = s_lab;   // num_clusters = dl.max(), EXCLUSIVE bound for merge

    // ---- dump dl; run starts (clusters are contiguous runs in visit order) ----
    for (int j = tid; j < NPTS; j += BLK) dlg[j] = (int)dl[j];
    for (int s = tid; s < NPTS; s += BLK) {
        int c = (int)dl[vor[s]];
        bool first = (s == 0) || ((int)dl[vor[s-1]] != c);
        if (first) startw[c] = s;
    }
    __syncthreads();

    // ---- counts / centres / class per cluster: O(n) total via runs ----
    for (int c = tid; c <= nclus; c += BLK) {
        int s0 = startw[c];
        int s1 = (c < nclus) ? startw[c+1] : NPTS;
        float ax = 0.f, ay = 0.f, az = 0.f;
        for (int s = s0; s < s1; ++s) {
            int j = vor[s];
            ax = ax + px[j]; ay = ay + py[j]; az = az + pz[j];
        }
        int cnt = s1 - s0;
        float fc = (float)cnt;
        countg[c] = cnt;
        cxg[c] = ax / fc; cyg[c] = ay / fc; czg[c] = az / fc;
        ccg[c] = lb[vor[s0]];   // cluster class == class of any member (mismatch forces new cluster)
    }
    for (int c = tid; c < NPTS; c += BLK) remapg[c] = c;
    __syncthreads();

    // ---- stable rank sort (counts desc, index asc) via O(C^2) pairwise rank ----
    int* cntL = (int*)(sm + 12288);            // dl/vor dead now
    for (int c = tid; c < nclus; c += BLK) cntL[c] = countg[c];
    __syncthreads();
    for (int c = tid; c < nclus; c += BLK) {
        int k = cntL[c];
        int r = 0;
        for (int c2 = 0; c2 < nclus; ++c2) {
            int k2 = cntL[c2];
            r += (int)((k2 > k) || ((k2 == k) && (c2 < c)));
        }
        orderg[r] = c;
    }
    __syncthreads();

    // ---- ordered arrays in LDS (points dead) ----
    float* ocx = px; float* ocy = py; float* ocz = pz;
    int* opack = lb;                            // (cluster_id<<4)|class
    int* okeep = (int*)(sm + 12288);
    for (int i = tid; i < nclus; i += BLK) {
        int o = orderg[i];
        ocx[i] = cxg[o]; ocy[i] = cyg[o]; ocz[i] = czg[o];
        opack[i] = (o << 4) | ccg[o];
        okeep[i] = 1;
    }
    __syncthreads();

    // ---- sequential merge loop (absorbers are never later absorbed -> 1-level remap) ----
    for (int i = 0; i < nclus; ++i) {
        if (okeep[i]) {
            int pk = opack[i];
            int cls_i = pk & 15;
            int idx_i = pk >> 4;
            float cxi = ocx[i], cyi = ocy[i], czi = ocz[i];
            float r2 = r2a[cls_i];
            for (int j = i + 1 + tid; j < nclus; j += BLK) {
                if (okeep[j]) {
                    int pj = opack[j];
                    if ((pj & 15) == cls_i) {
                        float ddx = ocx[j] - cxi, ddy = ocy[j] - cyi, ddz = ocz[j] - czi;
                        float dn = sqrtf((ddx*ddx + ddy*ddy) + ddz*ddz);
                        if (dn < r2) { okeep[j] = 0; remapg[pj >> 4] = idx_i; }
                    }
                }
            }
        }
        __syncthreads();
    }

    // ---- final relabel ----
    for (int p = tid; p < NPTS; p += BLK) out[p] = remapg[dlg[p]];
}

extern "C" void kernel_launch(void* const* d_in, const int* in_sizes, int n_in,
                              void* d_out, int out_size, void* d_ws, size_t ws_size,
                              hipStream_t stream) {
    const float* pts  = (const float*)d_in[0];   // [3072,3] f32
    const int*   lbl  = (const int*)d_in[1];     // [3072] i32
    const float* anch = (const float*)d_in[2];   // [10,3] f32
    frustum_cluster<<<dim3(1), dim3(BLK), 0, stream>>>(pts, lbl, anch, (int*)d_out, (int*)d_ws);
}